// Round 1
// baseline (84.668 us; speedup 1.0000x reference)
//
#include <hip/hip_runtime.h>
#include <hip/hip_bf16.h>

// Feature-wise low-rank causal attention, restructured:
//   scores[b,i,j] = x_i * x_j * S0[i,j],  S0[i,j] = scale*dot(Q_emb[i,:],K_emb[j,:])
//   out[b,i] = x_i + gate * sum_j attn[i,j] * x_j * cw[j],  cw[j]=dot(V_emb[j,:],out_proj)
// S0, cw are batch-independent -> precompute once (kernel P), then the per-batch
// work is a masked softmax over 256x256 with O(1) work per element (kernel M).
// |scores| <= ~0.1 so no max-subtraction needed; log2e folded into S0 -> native exp2.

#define DD 256
#define RK 64
#define NB 16              // batches per block in main kernel
#define LOG2E 1.4426950408889634f

__global__ __launch_bounds__(256) void precompute_kernel(
    const float* __restrict__ Qe, const float* __restrict__ Ke,
    const float* __restrict__ Ve, const float* __restrict__ op,
    float* __restrict__ s0t, float* __restrict__ cw) {
  const int j = blockIdx.x;     // 0..255
  const int i = threadIdx.x;    // 0..255
  __shared__ float krow[RK];
  __shared__ float oprj[RK];
  if (i < RK) {
    krow[i] = Ke[j * RK + i];
    oprj[i] = op[i];
  }
  __syncthreads();
  // S0T[j][i] = scale*log2e * dot(Q_emb[i,:], K_emb[j,:])
  float acc = 0.f;
  const float4* q4 = reinterpret_cast<const float4*>(Qe + i * RK);
#pragma unroll
  for (int r4 = 0; r4 < RK / 4; ++r4) {
    float4 q = q4[r4];
    acc += q.x * krow[r4 * 4 + 0] + q.y * krow[r4 * 4 + 1] +
           q.z * krow[r4 * 4 + 2] + q.w * krow[r4 * 4 + 3];
  }
  const float scale = 0.125f * LOG2E;   // 1/sqrt(64) * log2e
  s0t[j * DD + i] = acc * scale;
  if (j == 0) {
    float a2 = 0.f;
    const float4* v4 = reinterpret_cast<const float4*>(Ve + i * RK);
#pragma unroll
    for (int r4 = 0; r4 < RK / 4; ++r4) {
      float4 v = v4[r4];
      a2 += v.x * oprj[r4 * 4 + 0] + v.y * oprj[r4 * 4 + 1] +
            v.z * oprj[r4 * 4 + 2] + v.w * oprj[r4 * 4 + 3];
    }
    cw[i] = a2;
  }
}

// Main kernel: grid = 4 * (B/NB) blocks of 256 threads (4 waves).
// blockIdx.x = w * CHUNKS + chunk; rows i in [64w, 64w+64), lanes = i.
// Each wave streams NB/4 batches. S0T slice staged in LDS (shared by waves);
// per-wave (x_j, x_j*cw_j) float2 staged for broadcast reads.
__global__ __launch_bounds__(256) void attn_main(
    const float* __restrict__ x, const float* __restrict__ s0t,
    const float* __restrict__ cw, const float* __restrict__ gl,
    float* __restrict__ out, int B) {
  const int CHUNKS = B / NB;
  const int w = blockIdx.x / CHUNKS;
  const int chunk = blockIdx.x % CHUNKS;
  const int base = w * 64;
  const int jlim = base + 64;
  const int lane = threadIdx.x & 63;
  const int wave = threadIdx.x >> 6;

  __shared__ float s0l[DD * 64];     // [jlim][64] used
  __shared__ float2 xp[4][DD];       // per-wave (x_j, x_j*cw_j)

  // stage S0T rows [0,jlim), cols [base, base+64)
  for (int idx = threadIdx.x; idx < jlim * 64; idx += 256) {
    int j = idx >> 6, ii = idx & 63;
    s0l[idx] = s0t[j * DD + base + ii];
  }
  __syncthreads();

  const float gate = 1.f / (1.f + __expf(-gl[0]));

  const int b0 = chunk * NB + wave * (NB / 4);
  for (int bi = 0; bi < NB / 4; ++bi) {
    const int b = b0 + bi;
    const float* xb = x + b * DD;
    // stage per-wave (x_j, x_j*cw_j)
    for (int jv = lane; jv < jlim; jv += 64) {
      float xj = xb[jv];
      xp[wave][jv] = make_float2(xj, xj * cw[jv]);
    }
    __syncthreads();   // all waves have identical trip counts

    const float xi = xb[base + lane];
    float l = 0.f, acc = 0.f;
    // full (unmasked) part: j < base  (all lanes have i = base+lane >= j)
#pragma unroll 4
    for (int j = 0; j < base; ++j) {
      float2 p2 = xp[wave][j];
      float sj = s0l[j * 64 + lane];
      float s = (xi * p2.x) * sj;
      float p = exp2f(s);
      l += p;
      acc = fmaf(p, p2.y, acc);
    }
    // masked tail: j in [base, base+64), active iff (j-base) <= lane
#pragma unroll 8
    for (int jj = 0; jj < 64; ++jj) {
      int j = base + jj;
      float2 p2 = xp[wave][j];
      float sj = s0l[j * 64 + lane];
      float s = (xi * p2.x) * sj;
      float p = exp2f(s);
      p = (jj <= lane) ? p : 0.f;
      l += p;
      acc = fmaf(p, p2.y, acc);
    }
    out[b * DD + base + lane] = xi + gate * (acc / l);
  }
}

extern "C" void kernel_launch(void* const* d_in, const int* in_sizes, int n_in,
                              void* d_out, int out_size, void* d_ws, size_t ws_size,
                              hipStream_t stream) {
  const float* x  = (const float*)d_in[0];
  const float* Qe = (const float*)d_in[1];
  const float* Ke = (const float*)d_in[2];
  const float* Ve = (const float*)d_in[3];
  const float* op = (const float*)d_in[4];
  const float* gl = (const float*)d_in[5];
  float* out = (float*)d_out;

  const int B = in_sizes[0] / DD;      // 4096
  float* s0t = (float*)d_ws;           // 256*256 floats
  float* cw  = s0t + DD * DD;          // 256 floats  (needs ws >= 263168 B)

  precompute_kernel<<<DD, DD, 0, stream>>>(Qe, Ke, Ve, op, s0t, cw);
  attn_main<<<4 * (B / NB), 256, 0, stream>>>(x, s0t, cw, gl, out, B);
}

// Round 2
// 43.534 us; speedup vs baseline: 1.9449x; 1.9449x over previous
//
#include <hip/hip_runtime.h>
#include <hip/hip_bf16.h>

// Feature-wise low-rank causal attention, restructured:
//   scores[b,i,j] = x_i * x_j * S0[i,j],  S0[i,j] = scale*dot(Q_emb[i,:],K_emb[j,:])
//   out[b,i] = x_i + gate * sum_j attn[i,j] * x_j * cw[j],  cw[j]=dot(V_emb[j,:],out_proj)
// |scores| <= ~2 so no softmax max-subtraction needed; log2e folded into S0 -> v_exp_f32.
//
// Round-1 structure: block = 4 waves = all 256 rows of the SAME 4 batches.
//  - wave w handles rows i in [64w, 64w+64), lane = i - 64w
//  - S0 read straight from L2 (256KB, fully resident) as per-lane float4 (4 j's/load),
//    amortized over 4 concurrently-processed batches (4 independent exp2 chains -> ILP)
//  - LDS only holds x_j and x_j*cw_j per batch (8KB) -> 4 blocks/CU, 16 waves/CU

#define DD 256
#define RK 64
#define NBATCH 4
#define LOG2E 1.4426950408889634f

__global__ __launch_bounds__(256) void precompute_kernel(
    const float* __restrict__ Qe, const float* __restrict__ Ke,
    const float* __restrict__ Ve, const float* __restrict__ op,
    float* __restrict__ s0, float* __restrict__ cw) {
  const int i = blockIdx.x;     // query row
  const int j = threadIdx.x;    // key col
  __shared__ float qrow[RK];
  __shared__ float oprj[RK];
  if (j < RK) {
    qrow[j] = Qe[i * RK + j];
    oprj[j] = op[j];
  }
  __syncthreads();
  // s0[i][j] = scale*log2e * dot(Q_emb[i,:], K_emb[j,:])
  float acc = 0.f;
  const float4* k4 = reinterpret_cast<const float4*>(Ke + j * RK);
#pragma unroll
  for (int r4 = 0; r4 < RK / 4; ++r4) {
    float4 k = k4[r4];
    acc += k.x * qrow[r4 * 4 + 0] + k.y * qrow[r4 * 4 + 1] +
           k.z * qrow[r4 * 4 + 2] + k.w * qrow[r4 * 4 + 3];
  }
  const float scale = 0.125f * LOG2E;   // 1/sqrt(64) * log2e
  s0[i * DD + j] = acc * scale;
  if (i == 0) {
    float a2 = 0.f;
    const float4* v4 = reinterpret_cast<const float4*>(Ve + j * RK);
#pragma unroll
    for (int r4 = 0; r4 < RK / 4; ++r4) {
      float4 v = v4[r4];
      a2 += v.x * oprj[r4 * 4 + 0] + v.y * oprj[r4 * 4 + 1] +
            v.z * oprj[r4 * 4 + 2] + v.w * oprj[r4 * 4 + 3];
    }
    cw[j] = a2;
  }
}

__global__ __launch_bounds__(256, 4) void attn_main(
    const float* __restrict__ x, const float* __restrict__ s0,
    const float* __restrict__ cw, const float* __restrict__ gl,
    float* __restrict__ out) {
  const int lane = threadIdx.x & 63;
  const int w = threadIdx.x >> 6;
  const int b0 = blockIdx.x * NBATCH;

  __shared__ float xs[NBATCH][DD];   // x_j
  __shared__ float xc[NBATCH][DD];   // x_j * cw_j

  for (int idx = threadIdx.x; idx < NBATCH * DD; idx += 256) {
    int b = idx >> 8, j = idx & 255;
    float xj = x[(b0 + b) * DD + j];
    xs[b][j] = xj;
    xc[b][j] = xj * cw[j];
  }
  __syncthreads();

  const float gate = 1.f / (1.f + __expf(-gl[0]));
  const int i = w * 64 + lane;
  const float4* s0row = reinterpret_cast<const float4*>(s0 + i * DD);

  float xi[NBATCH], l[NBATCH], acc[NBATCH];
#pragma unroll
  for (int b = 0; b < NBATCH; ++b) {
    xi[b] = xs[b][i];
    l[b] = 0.f;
    acc[b] = 0.f;
  }

  const int gfull = w * 16;            // unmasked groups of 4 j's (j < 64w)
#pragma unroll 2
  for (int g = 0; g < gfull; ++g) {
    float4 s4 = s0row[g];
#pragma unroll
    for (int b = 0; b < NBATCH; ++b) {
      float4 xj4 = *reinterpret_cast<const float4*>(&xs[b][g * 4]);
      float4 xc4 = *reinterpret_cast<const float4*>(&xc[b][g * 4]);
      float p0 = __builtin_amdgcn_exp2f(xi[b] * xj4.x * s4.x);
      float p1 = __builtin_amdgcn_exp2f(xi[b] * xj4.y * s4.y);
      float p2 = __builtin_amdgcn_exp2f(xi[b] * xj4.z * s4.z);
      float p3 = __builtin_amdgcn_exp2f(xi[b] * xj4.w * s4.w);
      l[b] += p0 + p1 + p2 + p3;
      acc[b] = fmaf(p0, xc4.x, acc[b]);
      acc[b] = fmaf(p1, xc4.y, acc[b]);
      acc[b] = fmaf(p2, xc4.z, acc[b]);
      acc[b] = fmaf(p3, xc4.w, acc[b]);
    }
  }

  // masked tail: j in [64w, 64w+64), active iff (j - 64w) <= lane
#pragma unroll 2
  for (int t = 0; t < 16; ++t) {
    const int g = gfull + t;
    float4 s4 = s0row[g];
    const int jj = t * 4;
    const bool m0 = (jj + 0) <= lane;
    const bool m1 = (jj + 1) <= lane;
    const bool m2 = (jj + 2) <= lane;
    const bool m3 = (jj + 3) <= lane;
#pragma unroll
    for (int b = 0; b < NBATCH; ++b) {
      float4 xj4 = *reinterpret_cast<const float4*>(&xs[b][g * 4]);
      float4 xc4 = *reinterpret_cast<const float4*>(&xc[b][g * 4]);
      float p0 = __builtin_amdgcn_exp2f(xi[b] * xj4.x * s4.x);
      float p1 = __builtin_amdgcn_exp2f(xi[b] * xj4.y * s4.y);
      float p2 = __builtin_amdgcn_exp2f(xi[b] * xj4.z * s4.z);
      float p3 = __builtin_amdgcn_exp2f(xi[b] * xj4.w * s4.w);
      p0 = m0 ? p0 : 0.f;
      p1 = m1 ? p1 : 0.f;
      p2 = m2 ? p2 : 0.f;
      p3 = m3 ? p3 : 0.f;
      l[b] += p0 + p1 + p2 + p3;
      acc[b] = fmaf(p0, xc4.x, acc[b]);
      acc[b] = fmaf(p1, xc4.y, acc[b]);
      acc[b] = fmaf(p2, xc4.z, acc[b]);
      acc[b] = fmaf(p3, xc4.w, acc[b]);
    }
  }

#pragma unroll
  for (int b = 0; b < NBATCH; ++b) {
    out[(b0 + b) * DD + i] = xi[b] + gate * (acc[b] / l[b]);
  }
}

extern "C" void kernel_launch(void* const* d_in, const int* in_sizes, int n_in,
                              void* d_out, int out_size, void* d_ws, size_t ws_size,
                              hipStream_t stream) {
  const float* x  = (const float*)d_in[0];
  const float* Qe = (const float*)d_in[1];
  const float* Ke = (const float*)d_in[2];
  const float* Ve = (const float*)d_in[3];
  const float* op = (const float*)d_in[4];
  const float* gl = (const float*)d_in[5];
  float* out = (float*)d_out;

  const int B = in_sizes[0] / DD;      // 4096
  float* s0 = (float*)d_ws;            // 256*256 floats
  float* cw = s0 + DD * DD;            // 256 floats

  precompute_kernel<<<DD, DD, 0, stream>>>(Qe, Ke, Ve, op, s0, cw);
  attn_main<<<B / NBATCH, 256, 0, stream>>>(x, s0, cw, gl, out);
}